// Round 3
// baseline (1007.406 us; speedup 1.0000x reference)
//
#include <hip/hip_runtime.h>
#include <hip/hip_bf16.h>
#include <math.h>

#define D_MODEL 1792
#define D_INNER 3584
#define D_STATE 16
#define D_CONV  4
#define DT_RANK 112
#define NLAYER  4
#define LSEQ    512
#define XPROJ_N (DT_RANK + 2 * D_STATE) /* 144 */
#define KSPLIT  8                        /* x_proj split-K factor */
#define KCHUNK  (D_INNER / KSPLIT)       /* 448 */
#define SCH     32                       /* scan chunks */
#define SCL     (LSEQ / SCH)             /* 16 steps per chunk */
#define INSPLIT 2                        /* in_proj K-split */
#define OUTSPLIT 4                       /* out_proj K-split */

typedef __attribute__((ext_vector_type(8))) short bf16x8;
typedef __attribute__((ext_vector_type(8))) ushort u16x8;
typedef __attribute__((ext_vector_type(4))) ushort u16x4;
typedef __attribute__((ext_vector_type(4))) float f32x4;

__device__ __forceinline__ ushort f2bf(float f) {
    unsigned u = __float_as_uint(f);
    unsigned r = (u + 0x7FFFu + ((u >> 16) & 1u)) >> 16;
    return (ushort)r;
}

__device__ __forceinline__ u16x8 cvt8(const f32x4 a, const f32x4 b) {
    u16x8 v;
    v[0] = f2bf(a[0]); v[1] = f2bf(a[1]); v[2] = f2bf(a[2]); v[3] = f2bf(a[3]);
    v[4] = f2bf(b[0]); v[5] = f2bf(b[1]); v[6] = f2bf(b[2]); v[7] = f2bf(b[3]);
    return v;
}

// ---------------------------------------------------------------------------
// (optional residual += sum of OUTSPLIT partial slices, or embed gather)
// then LayerNorm.   mode: 0 = plain LN, 1 = add partials, 2 = embed gather.
// ---------------------------------------------------------------------------
__global__ __launch_bounds__(256) void add_ln_kernel(float* __restrict__ res,
                                                     const float* __restrict__ hidp,
                                                     const float* __restrict__ w,
                                                     const float* __restrict__ b,
                                                     float* __restrict__ out32,
                                                     ushort* __restrict__ out16,
                                                     int mode,
                                                     const int* __restrict__ ids,
                                                     const float* __restrict__ embed) {
    const int l = blockIdx.x;
    const int t = threadIdx.x;
    __shared__ float sbuf[8];
    float loc[7];
    float* row = res + (size_t)l * D_MODEL;
    const float* erow = (mode == 2) ? (embed + (size_t)ids[l] * D_MODEL) : nullptr;

    float sum = 0.f;
#pragma unroll
    for (int i = 0; i < 7; ++i) {
        int d = t + i * 256;
        float v;
        if (mode == 2) {
            v = erow[d]; row[d] = v;
        } else {
            v = row[d];
            if (mode == 1) {
                float hv = 0.f;
#pragma unroll
                for (int z = 0; z < OUTSPLIT; ++z)
                    hv += hidp[(size_t)z * LSEQ * D_MODEL + (size_t)l * D_MODEL + d];
                v += hv; row[d] = v;
            }
        }
        loc[i] = v;
        sum += v;
    }
#pragma unroll
    for (int o = 32; o > 0; o >>= 1) sum += __shfl_down(sum, o, 64);
    if ((t & 63) == 0) sbuf[t >> 6] = sum;
    __syncthreads();
    if (t == 0) sbuf[4] = sbuf[0] + sbuf[1] + sbuf[2] + sbuf[3];
    __syncthreads();
    const float mu = sbuf[4] * (1.f / D_MODEL);

    float vs = 0.f;
#pragma unroll
    for (int i = 0; i < 7; ++i) { float d0 = loc[i] - mu; vs += d0 * d0; }
#pragma unroll
    for (int o = 32; o > 0; o >>= 1) vs += __shfl_down(vs, o, 64);
    __syncthreads();
    if ((t & 63) == 0) sbuf[t >> 6] = vs;
    __syncthreads();
    if (t == 0) sbuf[4] = sbuf[0] + sbuf[1] + sbuf[2] + sbuf[3];
    __syncthreads();
    const float rstd = rsqrtf(sbuf[4] * (1.f / D_MODEL) + 1e-5f);

#pragma unroll
    for (int i = 0; i < 7; ++i) {
        int d = t + i * 256;
        float v = (loc[i] - mu) * rstd * w[d] + b[d];
        if (out16) out16[(size_t)l * D_MODEL + d] = f2bf(v);
        else       out32[(size_t)l * D_MODEL + d] = v;
    }
}

// ---------------------------------------------------------------------------
// bf16 MFMA GEMM (NT), 128x128 tile, BK=32, 4 waves 2x2, wave tile 64x64.
// A: bf16 activations via async global_load_lds.
// W: fp32 weights, reg-staged + converted to bf16 into LDS (saves the
//    separate 480 MB convert round-trip that cost 128 us/call).
// split-K over gridDim.z. LDS 16 KB.
// ---------------------------------------------------------------------------
template<int NSPLIT>
__global__ __launch_bounds__(256) void gemm128_mfma(const ushort* __restrict__ A, int lda,
                                                    const float* __restrict__ W,
                                                    float* __restrict__ C,
                                                    int N, int K) {
    constexpr int BK = 32;
    __shared__ ushort As[128 * BK];
    __shared__ ushort Bs[128 * BK];

    const int tid  = threadIdx.x;
    const int lane = tid & 63;
    const int wave = tid >> 6;
    const int m0 = blockIdx.y * 128;
    const int n0 = blockIdx.x * 128;
    const int wm = (wave >> 1) * 64;
    const int wn = (wave & 1) * 64;
    const int frow = lane & 15;
    const int fkg  = lane >> 4;
    const int kchunk = K / NSPLIT;
    const int kbase  = blockIdx.z * kchunk;
    const int M = gridDim.y * 128;

    f32x4 acc[4][4] = {};

    for (int it = 0; it < kchunk / BK; ++it) {
        const int k0 = kbase + it * BK;
        // A: async global->LDS, 128 rows x 32 bf16 = 512 chunks of 16 B
#pragma unroll
        for (int i = 0; i < 2; ++i) {
            int c = tid + i * 256;
            int row = c >> 2;
            int kc  = (c & 3) * 8;
            __builtin_amdgcn_global_load_lds(
                (const __attribute__((address_space(1))) void*)(A + (size_t)(m0 + row) * lda + k0 + kc),
                (__attribute__((address_space(3))) void*)(As + c * 8), 16, 0, 0);
        }
        // B: fp32 -> reg -> bf16 -> LDS (512 chunks of 8 elems)
        f32x4 w0[2], w1[2];
#pragma unroll
        for (int i = 0; i < 2; ++i) {
            int c = tid + i * 256;
            int row = c >> 2;
            int kc  = (c & 3) * 8;
            const float* p = W + (size_t)(n0 + row) * K + k0 + kc;
            w0[i] = *(const f32x4*)p;
            w1[i] = *(const f32x4*)(p + 4);
        }
#pragma unroll
        for (int i = 0; i < 2; ++i) {
            int c = tid + i * 256;
            *(u16x8*)(Bs + c * 8) = cvt8(w0[i], w1[i]);
        }
        __syncthreads();

        bf16x8 af[4];
#pragma unroll
        for (int i = 0; i < 4; ++i)
            af[i] = *(const bf16x8*)(As + (wm + i * 16 + frow) * BK + fkg * 8);

#pragma unroll
        for (int j = 0; j < 4; ++j) {
            bf16x8 bb = *(const bf16x8*)(Bs + (wn + j * 16 + frow) * BK + fkg * 8);
#pragma unroll
            for (int i = 0; i < 4; ++i)
                acc[i][j] = __builtin_amdgcn_mfma_f32_16x16x32_bf16(af[i], bb, acc[i][j], 0, 0, 0);
        }
        __syncthreads();
    }

    float* Cz = C + (size_t)blockIdx.z * M * N;
#pragma unroll
    for (int i = 0; i < 4; ++i) {
#pragma unroll
        for (int r = 0; r < 4; ++r) {
            int m = m0 + wm + i * 16 + fkg * 4 + r;
            float* cp = Cz + (size_t)m * N + n0 + wn + frow;
#pragma unroll
            for (int j = 0; j < 4; ++j)
                cp[j * 16] = acc[i][j][r];
        }
    }
}

// ---------------------------------------------------------------------------
// dt_proj GEMM: [512 x 128pad] x [3584 x 112]^T, fp32 weights inline-converted
// (zero-pad cols 112..127). 64(M) x 128(N) tile, BK=32. softplus+bias fused.
// ---------------------------------------------------------------------------
__global__ __launch_bounds__(256) void dt_gemm(const ushort* __restrict__ A,
                                               const float* __restrict__ Wdt,
                                               float* __restrict__ C,
                                               const float* __restrict__ bias) {
    constexpr int BM = 64;
    constexpr int BK = 32;
    constexpr int N = D_INNER;
    __shared__ ushort As[BM * BK];
    __shared__ ushort Bs[128 * BK];

    const int tid  = threadIdx.x;
    const int lane = tid & 63;
    const int wave = tid >> 6;
    const int m0 = blockIdx.y * BM;
    const int n0 = blockIdx.x * 128;
    const int wm = (wave >> 1) * 32;
    const int wn = (wave & 1) * 64;
    const int frow = lane & 15;
    const int fkg  = lane >> 4;

    f32x4 acc[2][4] = {};

    for (int it = 0; it < 128 / BK; ++it) {
        const int k0 = it * BK;
        {   // A: 64 rows x 32 bf16 -> 256 chunks of 16 B
            int row = tid >> 2;
            int kc  = (tid & 3) * 8;
            __builtin_amdgcn_global_load_lds(
                (const __attribute__((address_space(1))) void*)(A + (size_t)(m0 + row) * 128 + k0 + kc),
                (__attribute__((address_space(3))) void*)(As + tid * 8), 16, 0, 0);
        }
        // B: fp32 [3584][112] -> bf16 LDS with zero pad (8-aligned chunks)
        f32x4 w0[2], w1[2];
        int valid[2];
#pragma unroll
        for (int i = 0; i < 2; ++i) {
            int c = tid + i * 256;
            int row = c >> 2;
            int k   = k0 + (c & 3) * 8;
            valid[i] = (k < DT_RANK);
            const float* p = Wdt + (size_t)(n0 + row) * DT_RANK + (valid[i] ? k : 0);
            w0[i] = *(const f32x4*)p;
            w1[i] = *(const f32x4*)(p + 4);
        }
#pragma unroll
        for (int i = 0; i < 2; ++i) {
            int c = tid + i * 256;
            u16x8 v = {};
            if (valid[i]) v = cvt8(w0[i], w1[i]);
            *(u16x8*)(Bs + c * 8) = v;
        }
        __syncthreads();

        bf16x8 af[2];
#pragma unroll
        for (int i = 0; i < 2; ++i)
            af[i] = *(const bf16x8*)(As + (wm + i * 16 + frow) * BK + fkg * 8);

#pragma unroll
        for (int j = 0; j < 4; ++j) {
            bf16x8 bb = *(const bf16x8*)(Bs + (wn + j * 16 + frow) * BK + fkg * 8);
#pragma unroll
            for (int i = 0; i < 2; ++i)
                acc[i][j] = __builtin_amdgcn_mfma_f32_16x16x32_bf16(af[i], bb, acc[i][j], 0, 0, 0);
        }
        __syncthreads();
    }

    float bj[4];
#pragma unroll
    for (int j = 0; j < 4; ++j) bj[j] = bias[n0 + wn + frow + j * 16];

#pragma unroll
    for (int i = 0; i < 2; ++i) {
#pragma unroll
        for (int r = 0; r < 4; ++r) {
            int m = m0 + wm + i * 16 + fkg * 4 + r;
            float* cp = C + (size_t)m * N + n0 + wn + frow;
#pragma unroll
            for (int j = 0; j < 4; ++j) {
                float v = acc[i][j][r] + bj[j];
                v = (v > 20.f) ? v : __logf(1.f + __expf(v));
                cp[j * 16] = v;
            }
        }
    }
}

// ---------------------------------------------------------------------------
// x_proj split-K MFMA. A: bf16 activations (gload_lds). W: fp32 inline-cvt.
// ---------------------------------------------------------------------------
__global__ __launch_bounds__(256) void xproj_split(const ushort* __restrict__ xcbf,
                                                   const float* __restrict__ W,
                                                   float* __restrict__ xpart) {
    __shared__ ushort As[64 * 32];
    __shared__ ushort Ws[16 * 32];
    const int tid  = threadIdx.x;
    const int lane = tid & 63;
    const int wave = tid >> 6;
    const int n0 = blockIdx.x * 16;
    const int m0 = blockIdx.y * 64;
    const int z  = blockIdx.z;
    const int wm = wave * 16;
    const int frow = lane & 15;
    const int fkg  = lane >> 4;
    const int kbase = z * KCHUNK;

    f32x4 acc = {};

    for (int it = 0; it < KCHUNK / 32; ++it) {
        const int k0 = kbase + it * 32;
        {
            int row = tid >> 2;
            int kc  = (tid & 3) * 8;
            __builtin_amdgcn_global_load_lds(
                (const __attribute__((address_space(1))) void*)(xcbf + (size_t)(m0 + row) * D_INNER + k0 + kc),
                (__attribute__((address_space(3))) void*)(As + tid * 8), 16, 0, 0);
        }
        if (tid < 64) {   // W: 16 rows x 32 fp32 -> cvt -> 64 chunks of 16 B
            int row = tid >> 2;
            int kc  = (tid & 3) * 8;
            const float* p = W + (size_t)(n0 + row) * D_INNER + k0 + kc;
            f32x4 a = *(const f32x4*)p;
            f32x4 b = *(const f32x4*)(p + 4);
            *(u16x8*)(Ws + tid * 8) = cvt8(a, b);
        }
        __syncthreads();

        bf16x8 af = *(const bf16x8*)(As + (wm + frow) * 32 + fkg * 8);
        bf16x8 bb = *(const bf16x8*)(Ws + frow * 32 + fkg * 8);
        acc = __builtin_amdgcn_mfma_f32_16x16x32_bf16(af, bb, acc, 0, 0, 0);
        __syncthreads();
    }

#pragma unroll
    for (int r = 0; r < 4; ++r) {
        int m = m0 + wm + fkg * 4 + r;
        int n = n0 + frow;
        xpart[((size_t)z * LSEQ + m) * XPROJ_N + n] = acc[r];
    }
}

// ---------------------------------------------------------------------------
// Reduce x_proj split-K partials
// ---------------------------------------------------------------------------
__global__ __launch_bounds__(256) void xreduce_kernel(const float* __restrict__ xpart,
                                                      float* __restrict__ dbl,
                                                      ushort* __restrict__ dtb) {
    int idx = blockIdx.x * 256 + threadIdx.x;
    if (idx >= LSEQ * XPROJ_N) return;
    int m = idx / XPROJ_N;
    int n = idx - m * XPROJ_N;
    float s = 0.f;
#pragma unroll
    for (int z = 0; z < KSPLIT; ++z)
        s += xpart[(size_t)z * LSEQ * XPROJ_N + idx];
    dbl[idx] = s;
    if (n < DT_RANK)      dtb[m * 128 + n] = f2bf(s);
    else if (n < 128)     dtb[m * 128 + n] = 0;
}

// ---------------------------------------------------------------------------
// Causal depthwise conv + bias + SiLU, reducing the INSPLIT xz partials.
// 4 channels per thread (float4 path).
// ---------------------------------------------------------------------------
__global__ __launch_bounds__(256) void conv_silu_kernel(const float* __restrict__ xzp,
                                                        const float* __restrict__ cw,
                                                        const float* __restrict__ cb,
                                                        float* __restrict__ xc,
                                                        ushort* __restrict__ xcbf) {
    const size_t SL = (size_t)LSEQ * 2 * D_INNER;
    int idx = blockIdx.x * 256 + threadIdx.x;
    if (idx >= LSEQ * D_INNER / 4) return;
    int l  = idx / (D_INNER / 4);
    int c4 = (idx - l * (D_INNER / 4)) * 4;

    // per-channel tap weights (cw layout: [channel][tap])
    const f32x4 wc0 = *(const f32x4*)(cw + (size_t)(c4 + 0) * D_CONV);
    const f32x4 wc1 = *(const f32x4*)(cw + (size_t)(c4 + 1) * D_CONV);
    const f32x4 wc2 = *(const f32x4*)(cw + (size_t)(c4 + 2) * D_CONV);
    const f32x4 wc3 = *(const f32x4*)(cw + (size_t)(c4 + 3) * D_CONV);

    f32x4 s = *(const f32x4*)(cb + c4);
#pragma unroll
    for (int k = 0; k < D_CONV; ++k) {
        int ll = l - (D_CONV - 1) + k;
        if (ll >= 0) {
            const f32x4 v0 = *(const f32x4*)(xzp + (size_t)ll * (2 * D_INNER) + c4);
            const f32x4 v1 = *(const f32x4*)(xzp + SL + (size_t)ll * (2 * D_INNER) + c4);
            s[0] = fmaf(wc0[k], v0[0] + v1[0], s[0]);
            s[1] = fmaf(wc1[k], v0[1] + v1[1], s[1]);
            s[2] = fmaf(wc2[k], v0[2] + v1[2], s[2]);
            s[3] = fmaf(wc3[k], v0[3] + v1[3], s[3]);
        }
    }
    f32x4 o;
    u16x4 ob;
#pragma unroll
    for (int q = 0; q < 4; ++q) {
        const float sig = 1.f / (1.f + __expf(-s[q]));
        o[q] = s[q] * sig;
        ob[q] = f2bf(o[q]);
    }
    *(f32x4*)(xc + (size_t)idx * 4) = o;
    *(u16x4*)(xcbf + (size_t)idx * 4) = ob;
}

// ---------------------------------------------------------------------------
// Chunk-parallel selective scan (S1 / fix / S3). S3 reduces xz z-partials.
// ---------------------------------------------------------------------------
__global__ __launch_bounds__(256) void scan_part1(const float* __restrict__ dt,
                                                  const float* __restrict__ xc,
                                                  const float* __restrict__ dbl,
                                                  const float* __restrict__ A_log,
                                                  float* __restrict__ P,
                                                  float* __restrict__ F) {
    const int d = blockIdx.x * 256 + threadIdx.x;
    const int c = blockIdx.y;
    __shared__ float Bs[SCL][D_STATE];
    {
        int t = threadIdx.x;
        int ll = t >> 4, s = t & 15;
        Bs[ll][s] = dbl[(size_t)(c * SCL + ll) * XPROJ_N + DT_RANK + s];
    }
    float A2[D_STATE], h[D_STATE], p[D_STATE];
#pragma unroll
    for (int s = 0; s < D_STATE; ++s) {
        A2[s] = -__expf(A_log[(size_t)d * D_STATE + s]) * 1.4426950408889634f;
        h[s] = 0.f; p[s] = 1.f;
    }
    __syncthreads();

    for (int li0 = 0; li0 < SCL; li0 += 4) {
        float dtv4[4], xcv4[4];
#pragma unroll
        for (int q = 0; q < 4; ++q) {
            const int l = c * SCL + li0 + q;
            dtv4[q] = dt[(size_t)l * D_INNER + d];
            xcv4[q] = xc[(size_t)l * D_INNER + d];
        }
#pragma unroll
        for (int q = 0; q < 4; ++q) {
            const int li = li0 + q;
            const float dtv = dtv4[q];
            const float coef = dtv * xcv4[q];
#pragma unroll
            for (int s = 0; s < D_STATE; ++s) {
                float e = exp2f(dtv * A2[s]);
                h[s] = fmaf(e, h[s], coef * Bs[li][s]);
                p[s] *= e;
            }
        }
    }
    float* Pp = P + ((size_t)c * D_INNER + d) * D_STATE;
    float* Fp = F + ((size_t)c * D_INNER + d) * D_STATE;
#pragma unroll
    for (int v = 0; v < 4; ++v) {
        *(f32x4*)(Pp + v * 4) = *(f32x4*)(p + v * 4);
        *(f32x4*)(Fp + v * 4) = *(f32x4*)(h + v * 4);
    }
}

__global__ __launch_bounds__(256) void scan_fix(const float* __restrict__ P,
                                                const float* __restrict__ F,
                                                float* __restrict__ Hin) {
    const int idx = blockIdx.x * 256 + threadIdx.x;
    if (idx >= D_INNER * D_STATE) return;
    const size_t stride = (size_t)D_INNER * D_STATE;
    float h = 0.f;
#pragma unroll
    for (int c = 0; c < SCH; ++c) {
        Hin[c * stride + idx] = h;
        h = fmaf(P[c * stride + idx], h, F[c * stride + idx]);
    }
}

__global__ __launch_bounds__(256) void scan_part3(const float* __restrict__ dt,
                                                  const float* __restrict__ xc,
                                                  const float* __restrict__ dbl,
                                                  const float* __restrict__ A_log,
                                                  const float* __restrict__ Dp,
                                                  const float* __restrict__ xzp,
                                                  const float* __restrict__ Hin,
                                                  ushort* __restrict__ ybf) {
    const size_t SL = (size_t)LSEQ * 2 * D_INNER;
    const int d = blockIdx.x * 256 + threadIdx.x;
    const int c = blockIdx.y;
    __shared__ float Bs[SCL][D_STATE];
    __shared__ float Cs[SCL][D_STATE];
    {
        int t = threadIdx.x;
        int ll = t >> 4, s = t & 15;
        Bs[ll][s] = dbl[(size_t)(c * SCL + ll) * XPROJ_N + DT_RANK + s];
        Cs[ll][s] = dbl[(size_t)(c * SCL + ll) * XPROJ_N + DT_RANK + D_STATE + s];
    }
    float A2[D_STATE], h[D_STATE];
#pragma unroll
    for (int s = 0; s < D_STATE; ++s)
        A2[s] = -__expf(A_log[(size_t)d * D_STATE + s]) * 1.4426950408889634f;
    {
        const float* Hp = Hin + ((size_t)c * D_INNER + d) * D_STATE;
#pragma unroll
        for (int v = 0; v < 4; ++v)
            *(f32x4*)(h + v * 4) = *(const f32x4*)(Hp + v * 4);
    }
    const float Dd = Dp[d];
    __syncthreads();

    for (int li0 = 0; li0 < SCL; li0 += 4) {
        float dtv4[4], xcv4[4], zv4[4];
#pragma unroll
        for (int q = 0; q < 4; ++q) {
            const int l = c * SCL + li0 + q;
            dtv4[q] = dt[(size_t)l * D_INNER + d];
            xcv4[q] = xc[(size_t)l * D_INNER + d];
            zv4[q]  = xzp[(size_t)l * (2 * D_INNER) + D_INNER + d]
                    + xzp[SL + (size_t)l * (2 * D_INNER) + D_INNER + d];
        }
#pragma unroll
        for (int q = 0; q < 4; ++q) {
            const int li = li0 + q;
            const float dtv = dtv4[q];
            const float xcv = xcv4[q];
            const float coef = dtv * xcv;
            float a0 = 0.f, a1 = 0.f, a2 = 0.f, a3 = 0.f;
#pragma unroll
            for (int s = 0; s < D_STATE; s += 4) {
                float e0 = exp2f(dtv * A2[s + 0]);
                float e1 = exp2f(dtv * A2[s + 1]);
                float e2 = exp2f(dtv * A2[s + 2]);
                float e3 = exp2f(dtv * A2[s + 3]);
                h[s + 0] = fmaf(e0, h[s + 0], coef * Bs[li][s + 0]);
                h[s + 1] = fmaf(e1, h[s + 1], coef * Bs[li][s + 1]);
                h[s + 2] = fmaf(e2, h[s + 2], coef * Bs[li][s + 2]);
                h[s + 3] = fmaf(e3, h[s + 3], coef * Bs[li][s + 3]);
                a0 = fmaf(h[s + 0], Cs[li][s + 0], a0);
                a1 = fmaf(h[s + 1], Cs[li][s + 1], a1);
                a2 = fmaf(h[s + 2], Cs[li][s + 2], a2);
                a3 = fmaf(h[s + 3], Cs[li][s + 3], a3);
            }
            const float zv = zv4[q];
            const float sig = 1.f / (1.f + __expf(-zv));
            const float y = ((a0 + a1) + (a2 + a3) + Dd * xcv) * (zv * sig);
            ybf[(size_t)(c * SCL + li) * D_INNER + d] = f2bf(y);
        }
    }
}

// ---------------------------------------------------------------------------
extern "C" void kernel_launch(void* const* d_in, const int* in_sizes, int n_in,
                              void* d_out, int out_size, void* d_ws, size_t ws_size,
                              hipStream_t stream) {
    const int*   ids       = (const int*)d_in[0];
    const float* embed     = (const float*)d_in[1];
    const float* in_proj_w = (const float*)d_in[2];
    const float* conv_w    = (const float*)d_in[3];
    const float* conv_b    = (const float*)d_in[4];
    const float* x_proj_w  = (const float*)d_in[5];
    const float* dt_proj_w = (const float*)d_in[6];
    const float* dt_proj_b = (const float*)d_in[7];
    const float* A_log     = (const float*)d_in[8];
    const float* D_skip    = (const float*)d_in[9];
    const float* out_proj_w= (const float*)d_in[10];
    const float* norm_w    = (const float*)d_in[11];
    const float* norm_b    = (const float*)d_in[12];
    const float* fin_w     = (const float*)d_in[13];
    const float* fin_b     = (const float*)d_in[14];
    float* out = (float*)d_out;

    float* ws = (float*)d_ws;
    float* res    = ws; ws += LSEQ * D_MODEL;
    float* xzp    = ws; ws += (size_t)INSPLIT * LSEQ * 2 * D_INNER;
    float* xc     = ws; ws += (size_t)LSEQ * D_INNER;
    float* dbl    = ws; ws += LSEQ * XPROJ_N;
    float* dty    = ws; ws += (size_t)LSEQ * D_INNER;
    float* xpart  = ws; ws += (size_t)KSPLIT * LSEQ * XPROJ_N;
    float* Pbuf   = ws; ws += (size_t)SCH * D_INNER * D_STATE;
    float* Fbuf   = ws; ws += (size_t)SCH * D_INNER * D_STATE;
    float* HinB   = ws; ws += (size_t)SCH * D_INNER * D_STATE;
    ushort* hbf   = (ushort*)ws; ws += (LSEQ * D_MODEL) / 2;
    ushort* ybf   = (ushort*)ws; ws += (LSEQ * D_INNER) / 2;
    ushort* xcbf  = (ushort*)ws; ws += (LSEQ * D_INNER) / 2;
    ushort* dtb   = (ushort*)ws; ws += (LSEQ * 128) / 2;
    // out_proj partials alias P+F (2 x 7.34 MB >= OUTSPLIT x 512 x 1792 fp32).
    float* outp = Pbuf;

    for (int i = 0; i < NLAYER; ++i) {
        // layer 0: fused embed gather + LN; later layers: residual add + LN
        add_ln_kernel<<<LSEQ, 256, 0, stream>>>(
            res, outp, norm_w + (size_t)i * D_MODEL, norm_b + (size_t)i * D_MODEL,
            nullptr, hbf, i > 0 ? 1 : 2, ids, embed);

        // in_proj: [512 x 1792] x [7168 x 1792]^T, split-K 2 -> xzp
        gemm128_mfma<INSPLIT><<<dim3(2 * D_INNER / 128, LSEQ / 128, INSPLIT), 256, 0, stream>>>(
            hbf, D_MODEL, in_proj_w + (size_t)i * 2 * D_INNER * D_MODEL, xzp,
            2 * D_INNER, D_MODEL);

        conv_silu_kernel<<<(LSEQ * D_INNER / 4 + 255) / 256, 256, 0, stream>>>(
            xzp, conv_w + (size_t)i * D_INNER * D_CONV, conv_b + (size_t)i * D_INNER,
            xc, xcbf);

        xproj_split<<<dim3(XPROJ_N / 16, LSEQ / 64, KSPLIT), 256, 0, stream>>>(
            xcbf, x_proj_w + (size_t)i * XPROJ_N * D_INNER, xpart);
        xreduce_kernel<<<(LSEQ * XPROJ_N + 255) / 256, 256, 0, stream>>>(xpart, dbl, dtb);

        dt_gemm<<<dim3(D_INNER / 128, LSEQ / 64, 1), 256, 0, stream>>>(
            dtb, dt_proj_w + (size_t)i * D_INNER * DT_RANK, dty,
            dt_proj_b + (size_t)i * D_INNER);

        scan_part1<<<dim3(D_INNER / 256, SCH), 256, 0, stream>>>(
            dty, xc, dbl, A_log + (size_t)i * D_INNER * D_STATE, Pbuf, Fbuf);
        scan_fix<<<(D_INNER * D_STATE + 255) / 256, 256, 0, stream>>>(Pbuf, Fbuf, HinB);
        scan_part3<<<dim3(D_INNER / 256, SCH), 256, 0, stream>>>(
            dty, xc, dbl, A_log + (size_t)i * D_INNER * D_STATE,
            D_skip + (size_t)i * D_INNER, xzp, HinB, ybf);

        // out_proj: [512 x 3584] x [1792 x 3584]^T, split-K 4 -> outp (P/F alias)
        gemm128_mfma<OUTSPLIT><<<dim3(D_MODEL / 128, LSEQ / 128, OUTSPLIT), 256, 0, stream>>>(
            ybf, D_INNER, out_proj_w + (size_t)i * D_MODEL * D_INNER, outp,
            D_MODEL, D_INNER);
    }

    add_ln_kernel<<<LSEQ, 256, 0, stream>>>(res, outp, fin_w, fin_b, out, nullptr, 1,
                                            nullptr, nullptr);
}

// Round 4
// 933.189 us; speedup vs baseline: 1.0795x; 1.0795x over previous
//
#include <hip/hip_runtime.h>
#include <hip/hip_bf16.h>
#include <math.h>

#define D_MODEL 1792
#define D_INNER 3584
#define D_STATE 16
#define D_CONV  4
#define DT_RANK 112
#define NLAYER  4
#define LSEQ    512
#define XPROJ_N (DT_RANK + 2 * D_STATE) /* 144 */
#define KSPLIT  8                        /* x_proj split-K factor */
#define KCHUNK  (D_INNER / KSPLIT)       /* 448 */
#define SCH     32                       /* scan chunks */
#define SCL     (LSEQ / SCH)             /* 16 steps per chunk */
#define INSPLIT 2                        /* in_proj K-split */
#define OUTSPLIT 8                       /* out_proj K-split (448 blocks) */

typedef __attribute__((ext_vector_type(8))) short bf16x8;
typedef __attribute__((ext_vector_type(8))) ushort u16x8;
typedef __attribute__((ext_vector_type(4))) ushort u16x4;
typedef __attribute__((ext_vector_type(4))) float f32x4;

__device__ __forceinline__ ushort f2bf(float f) {
    unsigned u = __float_as_uint(f);
    unsigned r = (u + 0x7FFFu + ((u >> 16) & 1u)) >> 16;
    return (ushort)r;
}

__device__ __forceinline__ u16x8 cvt8(const f32x4 a, const f32x4 b) {
    u16x8 v;
    v[0] = f2bf(a[0]); v[1] = f2bf(a[1]); v[2] = f2bf(a[2]); v[3] = f2bf(a[3]);
    v[4] = f2bf(b[0]); v[5] = f2bf(b[1]); v[6] = f2bf(b[2]); v[7] = f2bf(b[3]);
    return v;
}

// ---------------------------------------------------------------------------
// (optional residual += sum of OUTSPLIT partial slices, or embed gather)
// then LayerNorm.   mode: 0 = plain LN, 1 = add partials, 2 = embed gather.
// ---------------------------------------------------------------------------
__global__ __launch_bounds__(256) void add_ln_kernel(float* __restrict__ res,
                                                     const float* __restrict__ hidp,
                                                     const float* __restrict__ w,
                                                     const float* __restrict__ b,
                                                     float* __restrict__ out32,
                                                     ushort* __restrict__ out16,
                                                     int mode,
                                                     const int* __restrict__ ids,
                                                     const float* __restrict__ embed) {
    const int l = blockIdx.x;
    const int t = threadIdx.x;
    __shared__ float sbuf[8];
    float loc[7];
    float* row = res + (size_t)l * D_MODEL;
    const float* erow = (mode == 2) ? (embed + (size_t)ids[l] * D_MODEL) : nullptr;

    float sum = 0.f;
#pragma unroll
    for (int i = 0; i < 7; ++i) {
        int d = t + i * 256;
        float v;
        if (mode == 2) {
            v = erow[d]; row[d] = v;
        } else {
            v = row[d];
            if (mode == 1) {
                float hv = 0.f;
#pragma unroll
                for (int z = 0; z < OUTSPLIT; ++z)
                    hv += hidp[(size_t)z * LSEQ * D_MODEL + (size_t)l * D_MODEL + d];
                v += hv; row[d] = v;
            }
        }
        loc[i] = v;
        sum += v;
    }
#pragma unroll
    for (int o = 32; o > 0; o >>= 1) sum += __shfl_down(sum, o, 64);
    if ((t & 63) == 0) sbuf[t >> 6] = sum;
    __syncthreads();
    if (t == 0) sbuf[4] = sbuf[0] + sbuf[1] + sbuf[2] + sbuf[3];
    __syncthreads();
    const float mu = sbuf[4] * (1.f / D_MODEL);

    float vs = 0.f;
#pragma unroll
    for (int i = 0; i < 7; ++i) { float d0 = loc[i] - mu; vs += d0 * d0; }
#pragma unroll
    for (int o = 32; o > 0; o >>= 1) vs += __shfl_down(vs, o, 64);
    __syncthreads();
    if ((t & 63) == 0) sbuf[t >> 6] = vs;
    __syncthreads();
    if (t == 0) sbuf[4] = sbuf[0] + sbuf[1] + sbuf[2] + sbuf[3];
    __syncthreads();
    const float rstd = rsqrtf(sbuf[4] * (1.f / D_MODEL) + 1e-5f);

#pragma unroll
    for (int i = 0; i < 7; ++i) {
        int d = t + i * 256;
        float v = (loc[i] - mu) * rstd * w[d] + b[d];
        if (out16) out16[(size_t)l * D_MODEL + d] = f2bf(v);
        else       out32[(size_t)l * D_MODEL + d] = v;
    }
}

// ---------------------------------------------------------------------------
// bf16 MFMA GEMM (NT), 128x128 tile, BK=32, 4 waves 2x2, wave tile 64x64.
// 2-PHASE DOUBLE-BUFFERED pipeline (issue-early / write-late):
//   per K-iter: issue next A (global_load_lds) + next B (fp32->regs) BEFORE
//   the current tile's ds_read+MFMA; cvt+ds_write B after; one barrier/iter.
// A: bf16 activations. W: fp32 weights inline-converted (no wcvt pass).
// split-K over gridDim.z. LDS 32 KB (2 x 16 KB).
// ---------------------------------------------------------------------------
template<int NSPLIT>
__global__ __launch_bounds__(256) void gemm128_mfma(const ushort* __restrict__ A, int lda,
                                                    const float* __restrict__ W,
                                                    float* __restrict__ C,
                                                    int N, int K) {
    constexpr int BK = 32;
    __shared__ ushort As[2][128 * BK];
    __shared__ ushort Bs[2][128 * BK];

    const int tid  = threadIdx.x;
    const int lane = tid & 63;
    const int wave = tid >> 6;
    const int m0 = blockIdx.y * 128;
    const int n0 = blockIdx.x * 128;
    const int wm = (wave >> 1) * 64;
    const int wn = (wave & 1) * 64;
    const int frow = lane & 15;
    const int fkg  = lane >> 4;
    const int kchunk = K / NSPLIT;
    const int kbase  = blockIdx.z * kchunk;
    const int M = gridDim.y * 128;
    const int nIter = kchunk / BK;

    // staging geometry: thread covers chunks c = tid and tid+256
    const int r0 = tid >> 2;            // rows 0..63
    const int r1 = r0 + 64;             // rows 64..127
    const int kc = (tid & 3) * 8;       // 8-elem column group

    f32x4 acc[4][4] = {};
    f32x4 wa0, wa1, wb0, wb1;           // B fp32 staging regs

    // ---- prologue: fill buffer 0 ----
    {
        __builtin_amdgcn_global_load_lds(
            (const __attribute__((address_space(1))) void*)(A + (size_t)(m0 + r0) * lda + kbase + kc),
            (__attribute__((address_space(3))) void*)(&As[0][tid * 8]), 16, 0, 0);
        __builtin_amdgcn_global_load_lds(
            (const __attribute__((address_space(1))) void*)(A + (size_t)(m0 + r1) * lda + kbase + kc),
            (__attribute__((address_space(3))) void*)(&As[0][(tid + 256) * 8]), 16, 0, 0);
        const float* p0 = W + (size_t)(n0 + r0) * K + kbase + kc;
        const float* p1 = W + (size_t)(n0 + r1) * K + kbase + kc;
        wa0 = *(const f32x4*)p0; wa1 = *(const f32x4*)(p0 + 4);
        wb0 = *(const f32x4*)p1; wb1 = *(const f32x4*)(p1 + 4);
        *(u16x8*)(&Bs[0][tid * 8]) = cvt8(wa0, wa1);
        *(u16x8*)(&Bs[0][(tid + 256) * 8]) = cvt8(wb0, wb1);
    }
    __syncthreads();   // drains prologue gload_lds (vmcnt0 before barrier)

    for (int it = 0; it < nIter; ++it) {
        const int cur = it & 1;
        const int nxt = cur ^ 1;
        const bool hasNext = (it + 1) < nIter;

        // ---- issue next-tile staging EARLY (flies under MFMA below) ----
        if (hasNext) {
            const int k0 = kbase + (it + 1) * BK;
            __builtin_amdgcn_global_load_lds(
                (const __attribute__((address_space(1))) void*)(A + (size_t)(m0 + r0) * lda + k0 + kc),
                (__attribute__((address_space(3))) void*)(&As[nxt][tid * 8]), 16, 0, 0);
            __builtin_amdgcn_global_load_lds(
                (const __attribute__((address_space(1))) void*)(A + (size_t)(m0 + r1) * lda + k0 + kc),
                (__attribute__((address_space(3))) void*)(&As[nxt][(tid + 256) * 8]), 16, 0, 0);
            const float* p0 = W + (size_t)(n0 + r0) * K + k0 + kc;
            const float* p1 = W + (size_t)(n0 + r1) * K + k0 + kc;
            wa0 = *(const f32x4*)p0; wa1 = *(const f32x4*)(p0 + 4);
            wb0 = *(const f32x4*)p1; wb1 = *(const f32x4*)(p1 + 4);
        }

        // ---- compute current tile ----
        bf16x8 af[4];
#pragma unroll
        for (int i = 0; i < 4; ++i)
            af[i] = *(const bf16x8*)(&As[cur][(wm + i * 16 + frow) * BK + fkg * 8]);

#pragma unroll
        for (int j = 0; j < 4; ++j) {
            bf16x8 bb = *(const bf16x8*)(&Bs[cur][(wn + j * 16 + frow) * BK + fkg * 8]);
#pragma unroll
            for (int i = 0; i < 4; ++i)
                acc[i][j] = __builtin_amdgcn_mfma_f32_16x16x32_bf16(af[i], bb, acc[i][j], 0, 0, 0);
        }

        // ---- late: convert + publish next B (regs arrived during MFMA) ----
        if (hasNext) {
            *(u16x8*)(&Bs[nxt][tid * 8]) = cvt8(wa0, wa1);
            *(u16x8*)(&Bs[nxt][(tid + 256) * 8]) = cvt8(wb0, wb1);
        }
        __syncthreads();
    }

    float* Cz = C + (size_t)blockIdx.z * M * N;
#pragma unroll
    for (int i = 0; i < 4; ++i) {
#pragma unroll
        for (int r = 0; r < 4; ++r) {
            int m = m0 + wm + i * 16 + fkg * 4 + r;
            float* cp = Cz + (size_t)m * N + n0 + wn + frow;
#pragma unroll
            for (int j = 0; j < 4; ++j)
                cp[j * 16] = acc[i][j][r];
        }
    }
}

// ---------------------------------------------------------------------------
// dt_proj GEMM: [512 x 128pad] x [3584 x 112]^T, fp32 weights inline-converted
// (zero-pad cols 112..127). 64(M) x 128(N) tile, BK=32. softplus+bias fused.
// ---------------------------------------------------------------------------
__global__ __launch_bounds__(256) void dt_gemm(const ushort* __restrict__ A,
                                               const float* __restrict__ Wdt,
                                               float* __restrict__ C,
                                               const float* __restrict__ bias) {
    constexpr int BM = 64;
    constexpr int BK = 32;
    constexpr int N = D_INNER;
    __shared__ ushort As[BM * BK];
    __shared__ ushort Bs[128 * BK];

    const int tid  = threadIdx.x;
    const int lane = tid & 63;
    const int wave = tid >> 6;
    const int m0 = blockIdx.y * BM;
    const int n0 = blockIdx.x * 128;
    const int wm = (wave >> 1) * 32;
    const int wn = (wave & 1) * 64;
    const int frow = lane & 15;
    const int fkg  = lane >> 4;

    f32x4 acc[2][4] = {};

    for (int it = 0; it < 128 / BK; ++it) {
        const int k0 = it * BK;
        {   // A: 64 rows x 32 bf16 -> 256 chunks of 16 B
            int row = tid >> 2;
            int kcA = (tid & 3) * 8;
            __builtin_amdgcn_global_load_lds(
                (const __attribute__((address_space(1))) void*)(A + (size_t)(m0 + row) * 128 + k0 + kcA),
                (__attribute__((address_space(3))) void*)(As + tid * 8), 16, 0, 0);
        }
        // B: fp32 [3584][112] -> bf16 LDS with zero pad (8-aligned chunks)
        f32x4 w0[2], w1[2];
        int valid[2];
#pragma unroll
        for (int i = 0; i < 2; ++i) {
            int c = tid + i * 256;
            int row = c >> 2;
            int k   = k0 + (c & 3) * 8;
            valid[i] = (k < DT_RANK);
            const float* p = Wdt + (size_t)(n0 + row) * DT_RANK + (valid[i] ? k : 0);
            w0[i] = *(const f32x4*)p;
            w1[i] = *(const f32x4*)(p + 4);
        }
#pragma unroll
        for (int i = 0; i < 2; ++i) {
            int c = tid + i * 256;
            u16x8 v = {};
            if (valid[i]) v = cvt8(w0[i], w1[i]);
            *(u16x8*)(Bs + c * 8) = v;
        }
        __syncthreads();

        bf16x8 af[2];
#pragma unroll
        for (int i = 0; i < 2; ++i)
            af[i] = *(const bf16x8*)(As + (wm + i * 16 + frow) * BK + fkg * 8);

#pragma unroll
        for (int j = 0; j < 4; ++j) {
            bf16x8 bb = *(const bf16x8*)(Bs + (wn + j * 16 + frow) * BK + fkg * 8);
#pragma unroll
            for (int i = 0; i < 2; ++i)
                acc[i][j] = __builtin_amdgcn_mfma_f32_16x16x32_bf16(af[i], bb, acc[i][j], 0, 0, 0);
        }
        __syncthreads();
    }

    float bj[4];
#pragma unroll
    for (int j = 0; j < 4; ++j) bj[j] = bias[n0 + wn + frow + j * 16];

#pragma unroll
    for (int i = 0; i < 2; ++i) {
#pragma unroll
        for (int r = 0; r < 4; ++r) {
            int m = m0 + wm + i * 16 + fkg * 4 + r;
            float* cp = C + (size_t)m * N + n0 + wn + frow;
#pragma unroll
            for (int j = 0; j < 4; ++j) {
                float v = acc[i][j][r] + bj[j];
                v = (v > 20.f) ? v : __logf(1.f + __expf(v));
                cp[j * 16] = v;
            }
        }
    }
}

// ---------------------------------------------------------------------------
// x_proj split-K MFMA. A: bf16 activations (gload_lds). W: fp32 inline-cvt.
// ---------------------------------------------------------------------------
__global__ __launch_bounds__(256) void xproj_split(const ushort* __restrict__ xcbf,
                                                   const float* __restrict__ W,
                                                   float* __restrict__ xpart) {
    __shared__ ushort As[64 * 32];
    __shared__ ushort Ws[16 * 32];
    const int tid  = threadIdx.x;
    const int lane = tid & 63;
    const int wave = tid >> 6;
    const int n0 = blockIdx.x * 16;
    const int m0 = blockIdx.y * 64;
    const int z  = blockIdx.z;
    const int wm = wave * 16;
    const int frow = lane & 15;
    const int fkg  = lane >> 4;
    const int kbase = z * KCHUNK;

    f32x4 acc = {};

    for (int it = 0; it < KCHUNK / 32; ++it) {
        const int k0 = kbase + it * 32;
        {
            int row = tid >> 2;
            int kc  = (tid & 3) * 8;
            __builtin_amdgcn_global_load_lds(
                (const __attribute__((address_space(1))) void*)(xcbf + (size_t)(m0 + row) * D_INNER + k0 + kc),
                (__attribute__((address_space(3))) void*)(As + tid * 8), 16, 0, 0);
        }
        if (tid < 64) {   // W: 16 rows x 32 fp32 -> cvt -> 64 chunks of 16 B
            int row = tid >> 2;
            int kc  = (tid & 3) * 8;
            const float* p = W + (size_t)(n0 + row) * D_INNER + k0 + kc;
            f32x4 a = *(const f32x4*)p;
            f32x4 b = *(const f32x4*)(p + 4);
            *(u16x8*)(Ws + tid * 8) = cvt8(a, b);
        }
        __syncthreads();

        bf16x8 af = *(const bf16x8*)(As + (wm + frow) * 32 + fkg * 8);
        bf16x8 bb = *(const bf16x8*)(Ws + frow * 32 + fkg * 8);
        acc = __builtin_amdgcn_mfma_f32_16x16x32_bf16(af, bb, acc, 0, 0, 0);
        __syncthreads();
    }

#pragma unroll
    for (int r = 0; r < 4; ++r) {
        int m = m0 + wm + fkg * 4 + r;
        int n = n0 + frow;
        xpart[((size_t)z * LSEQ + m) * XPROJ_N + n] = acc[r];
    }
}

// ---------------------------------------------------------------------------
// Reduce x_proj split-K partials
// ---------------------------------------------------------------------------
__global__ __launch_bounds__(256) void xreduce_kernel(const float* __restrict__ xpart,
                                                      float* __restrict__ dbl,
                                                      ushort* __restrict__ dtb) {
    int idx = blockIdx.x * 256 + threadIdx.x;
    if (idx >= LSEQ * XPROJ_N) return;
    int m = idx / XPROJ_N;
    int n = idx - m * XPROJ_N;
    float s = 0.f;
#pragma unroll
    for (int z = 0; z < KSPLIT; ++z)
        s += xpart[(size_t)z * LSEQ * XPROJ_N + idx];
    dbl[idx] = s;
    if (n < DT_RANK)      dtb[m * 128 + n] = f2bf(s);
    else if (n < 128)     dtb[m * 128 + n] = 0;
}

// ---------------------------------------------------------------------------
// Causal depthwise conv + bias + SiLU, reducing the INSPLIT xz partials.
// 4 channels per thread (float4 path).
// ---------------------------------------------------------------------------
__global__ __launch_bounds__(256) void conv_silu_kernel(const float* __restrict__ xzp,
                                                        const float* __restrict__ cw,
                                                        const float* __restrict__ cb,
                                                        float* __restrict__ xc,
                                                        ushort* __restrict__ xcbf) {
    const size_t SL = (size_t)LSEQ * 2 * D_INNER;
    int idx = blockIdx.x * 256 + threadIdx.x;
    if (idx >= LSEQ * D_INNER / 4) return;
    int l  = idx / (D_INNER / 4);
    int c4 = (idx - l * (D_INNER / 4)) * 4;

    // per-channel tap weights (cw layout: [channel][tap])
    const f32x4 wc0 = *(const f32x4*)(cw + (size_t)(c4 + 0) * D_CONV);
    const f32x4 wc1 = *(const f32x4*)(cw + (size_t)(c4 + 1) * D_CONV);
    const f32x4 wc2 = *(const f32x4*)(cw + (size_t)(c4 + 2) * D_CONV);
    const f32x4 wc3 = *(const f32x4*)(cw + (size_t)(c4 + 3) * D_CONV);

    f32x4 s = *(const f32x4*)(cb + c4);
#pragma unroll
    for (int k = 0; k < D_CONV; ++k) {
        int ll = l - (D_CONV - 1) + k;
        if (ll >= 0) {
            const f32x4 v0 = *(const f32x4*)(xzp + (size_t)ll * (2 * D_INNER) + c4);
            const f32x4 v1 = *(const f32x4*)(xzp + SL + (size_t)ll * (2 * D_INNER) + c4);
            s[0] = fmaf(wc0[k], v0[0] + v1[0], s[0]);
            s[1] = fmaf(wc1[k], v0[1] + v1[1], s[1]);
            s[2] = fmaf(wc2[k], v0[2] + v1[2], s[2]);
            s[3] = fmaf(wc3[k], v0[3] + v1[3], s[3]);
        }
    }
    f32x4 o;
    u16x4 ob;
#pragma unroll
    for (int q = 0; q < 4; ++q) {
        const float sig = 1.f / (1.f + __expf(-s[q]));
        o[q] = s[q] * sig;
        ob[q] = f2bf(o[q]);
    }
    *(f32x4*)(xc + (size_t)idx * 4) = o;
    *(u16x4*)(xcbf + (size_t)idx * 4) = ob;
}

// ---------------------------------------------------------------------------
// Chunk-parallel selective scan (S1 / fix / S3). S3 reduces xz z-partials.
// ---------------------------------------------------------------------------
__global__ __launch_bounds__(256) void scan_part1(const float* __restrict__ dt,
                                                  const float* __restrict__ xc,
                                                  const float* __restrict__ dbl,
                                                  const float* __restrict__ A_log,
                                                  float* __restrict__ P,
                                                  float* __restrict__ F) {
    const int d = blockIdx.x * 256 + threadIdx.x;
    const int c = blockIdx.y;
    __shared__ float Bs[SCL][D_STATE];
    {
        int t = threadIdx.x;
        int ll = t >> 4, s = t & 15;
        Bs[ll][s] = dbl[(size_t)(c * SCL + ll) * XPROJ_N + DT_RANK + s];
    }
    float A2[D_STATE], h[D_STATE], p[D_STATE];
#pragma unroll
    for (int s = 0; s < D_STATE; ++s) {
        A2[s] = -__expf(A_log[(size_t)d * D_STATE + s]) * 1.4426950408889634f;
        h[s] = 0.f; p[s] = 1.f;
    }
    __syncthreads();

    for (int li0 = 0; li0 < SCL; li0 += 4) {
        float dtv4[4], xcv4[4];
#pragma unroll
        for (int q = 0; q < 4; ++q) {
            const int l = c * SCL + li0 + q;
            dtv4[q] = dt[(size_t)l * D_INNER + d];
            xcv4[q] = xc[(size_t)l * D_INNER + d];
        }
#pragma unroll
        for (int q = 0; q < 4; ++q) {
            const int li = li0 + q;
            const float dtv = dtv4[q];
            const float coef = dtv * xcv4[q];
#pragma unroll
            for (int s = 0; s < D_STATE; ++s) {
                float e = exp2f(dtv * A2[s]);
                h[s] = fmaf(e, h[s], coef * Bs[li][s]);
                p[s] *= e;
            }
        }
    }
    float* Pp = P + ((size_t)c * D_INNER + d) * D_STATE;
    float* Fp = F + ((size_t)c * D_INNER + d) * D_STATE;
#pragma unroll
    for (int v = 0; v < 4; ++v) {
        *(f32x4*)(Pp + v * 4) = *(f32x4*)(p + v * 4);
        *(f32x4*)(Fp + v * 4) = *(f32x4*)(h + v * 4);
    }
}

__global__ __launch_bounds__(256) void scan_fix(const float* __restrict__ P,
                                                const float* __restrict__ F,
                                                float* __restrict__ Hin) {
    const int idx = blockIdx.x * 256 + threadIdx.x;
    if (idx >= D_INNER * D_STATE) return;
    const size_t stride = (size_t)D_INNER * D_STATE;
    float h = 0.f;
#pragma unroll
    for (int c = 0; c < SCH; ++c) {
        Hin[c * stride + idx] = h;
        h = fmaf(P[c * stride + idx], h, F[c * stride + idx]);
    }
}

__global__ __launch_bounds__(256) void scan_part3(const float* __restrict__ dt,
                                                  const float* __restrict__ xc,
                                                  const float* __restrict__ dbl,
                                                  const float* __restrict__ A_log,
                                                  const float* __restrict__ Dp,
                                                  const float* __restrict__ xzp,
                                                  const float* __restrict__ Hin,
                                                  ushort* __restrict__ ybf) {
    const size_t SL = (size_t)LSEQ * 2 * D_INNER;
    const int d = blockIdx.x * 256 + threadIdx.x;
    const int c = blockIdx.y;
    __shared__ float Bs[SCL][D_STATE];
    __shared__ float Cs[SCL][D_STATE];
    {
        int t = threadIdx.x;
        int ll = t >> 4, s = t & 15;
        Bs[ll][s] = dbl[(size_t)(c * SCL + ll) * XPROJ_N + DT_RANK + s];
        Cs[ll][s] = dbl[(size_t)(c * SCL + ll) * XPROJ_N + DT_RANK + D_STATE + s];
    }
    float A2[D_STATE], h[D_STATE];
#pragma unroll
    for (int s = 0; s < D_STATE; ++s)
        A2[s] = -__expf(A_log[(size_t)d * D_STATE + s]) * 1.4426950408889634f;
    {
        const float* Hp = Hin + ((size_t)c * D_INNER + d) * D_STATE;
#pragma unroll
        for (int v = 0; v < 4; ++v)
            *(f32x4*)(h + v * 4) = *(const f32x4*)(Hp + v * 4);
    }
    const float Dd = Dp[d];
    __syncthreads();

    for (int li0 = 0; li0 < SCL; li0 += 4) {
        float dtv4[4], xcv4[4], zv4[4];
#pragma unroll
        for (int q = 0; q < 4; ++q) {
            const int l = c * SCL + li0 + q;
            dtv4[q] = dt[(size_t)l * D_INNER + d];
            xcv4[q] = xc[(size_t)l * D_INNER + d];
            zv4[q]  = xzp[(size_t)l * (2 * D_INNER) + D_INNER + d]
                    + xzp[SL + (size_t)l * (2 * D_INNER) + D_INNER + d];
        }
#pragma unroll
        for (int q = 0; q < 4; ++q) {
            const int li = li0 + q;
            const float dtv = dtv4[q];
            const float xcv = xcv4[q];
            const float coef = dtv * xcv;
            float a0 = 0.f, a1 = 0.f, a2 = 0.f, a3 = 0.f;
#pragma unroll
            for (int s = 0; s < D_STATE; s += 4) {
                float e0 = exp2f(dtv * A2[s + 0]);
                float e1 = exp2f(dtv * A2[s + 1]);
                float e2 = exp2f(dtv * A2[s + 2]);
                float e3 = exp2f(dtv * A2[s + 3]);
                h[s + 0] = fmaf(e0, h[s + 0], coef * Bs[li][s + 0]);
                h[s + 1] = fmaf(e1, h[s + 1], coef * Bs[li][s + 1]);
                h[s + 2] = fmaf(e2, h[s + 2], coef * Bs[li][s + 2]);
                h[s + 3] = fmaf(e3, h[s + 3], coef * Bs[li][s + 3]);
                a0 = fmaf(h[s + 0], Cs[li][s + 0], a0);
                a1 = fmaf(h[s + 1], Cs[li][s + 1], a1);
                a2 = fmaf(h[s + 2], Cs[li][s + 2], a2);
                a3 = fmaf(h[s + 3], Cs[li][s + 3], a3);
            }
            const float zv = zv4[q];
            const float sig = 1.f / (1.f + __expf(-zv));
            const float y = ((a0 + a1) + (a2 + a3) + Dd * xcv) * (zv * sig);
            ybf[(size_t)(c * SCL + li) * D_INNER + d] = f2bf(y);
        }
    }
}

// ---------------------------------------------------------------------------
extern "C" void kernel_launch(void* const* d_in, const int* in_sizes, int n_in,
                              void* d_out, int out_size, void* d_ws, size_t ws_size,
                              hipStream_t stream) {
    const int*   ids       = (const int*)d_in[0];
    const float* embed     = (const float*)d_in[1];
    const float* in_proj_w = (const float*)d_in[2];
    const float* conv_w    = (const float*)d_in[3];
    const float* conv_b    = (const float*)d_in[4];
    const float* x_proj_w  = (const float*)d_in[5];
    const float* dt_proj_w = (const float*)d_in[6];
    const float* dt_proj_b = (const float*)d_in[7];
    const float* A_log     = (const float*)d_in[8];
    const float* D_skip    = (const float*)d_in[9];
    const float* out_proj_w= (const float*)d_in[10];
    const float* norm_w    = (const float*)d_in[11];
    const float* norm_b    = (const float*)d_in[12];
    const float* fin_w     = (const float*)d_in[13];
    const float* fin_b     = (const float*)d_in[14];
    float* out = (float*)d_out;

    float* ws = (float*)d_ws;
    float* res    = ws; ws += LSEQ * D_MODEL;
    float* xzp    = ws; ws += (size_t)INSPLIT * LSEQ * 2 * D_INNER;
    float* xc     = ws; ws += (size_t)LSEQ * D_INNER;
    float* dbl    = ws; ws += LSEQ * XPROJ_N;
    float* dty    = ws; ws += (size_t)LSEQ * D_INNER;
    float* xpart  = ws; ws += (size_t)KSPLIT * LSEQ * XPROJ_N;
    float* Pbuf   = ws; ws += (size_t)SCH * D_INNER * D_STATE;
    float* Fbuf   = ws; ws += (size_t)SCH * D_INNER * D_STATE;
    float* HinB   = ws; ws += (size_t)SCH * D_INNER * D_STATE;
    float* outp   = ws; ws += (size_t)OUTSPLIT * LSEQ * D_MODEL;
    ushort* hbf   = (ushort*)ws; ws += (LSEQ * D_MODEL) / 2;
    ushort* ybf   = (ushort*)ws; ws += (LSEQ * D_INNER) / 2;
    ushort* xcbf  = (ushort*)ws; ws += (LSEQ * D_INNER) / 2;
    ushort* dtb   = (ushort*)ws; ws += (LSEQ * 128) / 2;

    for (int i = 0; i < NLAYER; ++i) {
        // layer 0: fused embed gather + LN; later layers: residual add + LN
        add_ln_kernel<<<LSEQ, 256, 0, stream>>>(
            res, outp, norm_w + (size_t)i * D_MODEL, norm_b + (size_t)i * D_MODEL,
            nullptr, hbf, i > 0 ? 1 : 2, ids, embed);

        // in_proj: [512 x 1792] x [7168 x 1792]^T, split-K 2 -> xzp
        gemm128_mfma<INSPLIT><<<dim3(2 * D_INNER / 128, LSEQ / 128, INSPLIT), 256, 0, stream>>>(
            hbf, D_MODEL, in_proj_w + (size_t)i * 2 * D_INNER * D_MODEL, xzp,
            2 * D_INNER, D_MODEL);

        conv_silu_kernel<<<(LSEQ * D_INNER / 4 + 255) / 256, 256, 0, stream>>>(
            xzp, conv_w + (size_t)i * D_INNER * D_CONV, conv_b + (size_t)i * D_INNER,
            xc, xcbf);

        xproj_split<<<dim3(XPROJ_N / 16, LSEQ / 64, KSPLIT), 256, 0, stream>>>(
            xcbf, x_proj_w + (size_t)i * XPROJ_N * D_INNER, xpart);
        xreduce_kernel<<<(LSEQ * XPROJ_N + 255) / 256, 256, 0, stream>>>(xpart, dbl, dtb);

        dt_gemm<<<dim3(D_INNER / 128, LSEQ / 64, 1), 256, 0, stream>>>(
            dtb, dt_proj_w + (size_t)i * D_INNER * DT_RANK, dty,
            dt_proj_b + (size_t)i * D_INNER);

        scan_part1<<<dim3(D_INNER / 256, SCH), 256, 0, stream>>>(
            dty, xc, dbl, A_log + (size_t)i * D_INNER * D_STATE, Pbuf, Fbuf);
        scan_fix<<<(D_INNER * D_STATE + 255) / 256, 256, 0, stream>>>(Pbuf, Fbuf, HinB);
        scan_part3<<<dim3(D_INNER / 256, SCH), 256, 0, stream>>>(
            dty, xc, dbl, A_log + (size_t)i * D_INNER * D_STATE,
            D_skip + (size_t)i * D_INNER, xzp, HinB, ybf);

        // out_proj: [512 x 3584] x [1792 x 3584]^T, split-K 8 -> outp
        gemm128_mfma<OUTSPLIT><<<dim3(D_MODEL / 128, LSEQ / 128, OUTSPLIT), 256, 0, stream>>>(
            ybf, D_INNER, out_proj_w + (size_t)i * D_MODEL * D_INNER, outp,
            D_MODEL, D_INNER);
    }

    add_ln_kernel<<<LSEQ, 256, 0, stream>>>(res, outp, fin_w, fin_b, out, nullptr, 1,
                                            nullptr, nullptr);
}